// Round 5
// baseline (935.330 us; speedup 1.0000x reference)
//
#include <hip/hip_runtime.h>
#include <stdint.h>

#define Bn 4
#define Sn 2048
#define Hn 1024
#define Ln 4
#define Mn (Bn*Sn)          // 8192 rows
#define CHUNK 32
#define NCH (Sn/CHUNK)      // 64

typedef __bf16 bf16x8 __attribute__((ext_vector_type(8)));
typedef float  f32x4  __attribute__((ext_vector_type(4)));
typedef uint32_t u32;

__device__ __forceinline__ unsigned short f2bf(float f) {
  uint32_t u = __float_as_uint(f);
  uint32_t r = (u + 0x7FFFu + ((u >> 16) & 1u)) >> 16;
  return (unsigned short)r;
}

__device__ __forceinline__ void gload_lds16(const void* g, void* l) {
  __builtin_amdgcn_global_load_lds((const __attribute__((address_space(1))) void*)g,
                                   (__attribute__((address_space(3))) void*)l, 16, 0, 0);
}

// ---------------- cast f32 -> bf16 (vectorized) ----------------
__global__ __launch_bounds__(256) void cast_f32_bf16(const float* __restrict__ src,
                                                     unsigned short* __restrict__ dst, int n4) {
  int i = blockIdx.x * 256 + threadIdx.x;
  if (i >= n4) return;
  float4 v = reinterpret_cast<const float4*>(src)[i];
  ushort4 o;
  o.x = f2bf(v.x); o.y = f2bf(v.y); o.z = f2bf(v.z); o.w = f2bf(v.w);
  reinterpret_cast<ushort4*>(dst)[i] = o;
}

// ---------------- GEMM: out[M,N] = act[M,K](bf16) @ W[N,K]^T (bf16) + bias ----------------
// 256x256 tile, BK=64, 8 waves (2M x 4N), 512 threads, 128 KiB LDS double-buffer.
//
// ROUND-5: TRUE counted vmcnt with prefetch depth = 2 K-tiles. Rounds 1-4 all ended
// each K-tile with an effective vmcnt(0) drain of loads issued at the top of the
// SAME tile (three different sync structures, identical 57 us) — the T4 anti-pattern.
// Now: tile t computes buf b; after a barrier confirming all waves retired reads of
// buf b, issue tile t+2's 8 loads into buf b; VMW(8) waits only the OLDEST 8 (tile
// t+1's, issued a full tile ago) while t+2's stay in flight; barrier. No drain in
// the main loop.
//
// Kept (verified): asm ds_read_b128 (invisible to the waitcnt pass's LDS-DMA alias
// analysis, +10% r3), 2-way slot-XOR swizzle (bank conflicts = 0, +7% r2), 16B
// global_load_lds linear dest + inverse-permuted global source (rule #21), setprio
// around MFMA clusters, sched_barrier(0) after every waitcnt (rule #18), counted
// lgkm gates intra-tile (r4).
//
// LDS layout per matrix: [2 buf][2 khalf][256 rows][4 slots of 16B], region = 16 KB.
// Swizzle: phys_slot = logical_slot ^ ((row>>1) & 3).
//
// Pipeline invariants:
//  entry(tile t, buf b): buf b's loads LANDED (prev tile's VMW(8)+barrier);
//                        tile t+1's 8 loads IN FLIGHT into buf b^1.
//  WAR: STG4(t+2 -> buf b) issues after the barrier following this tile's
//       lgkm(0)-retired reads of buf b (all waves done reading).
//  RAW: VMW(8) with 16 outstanding lands the oldest 8 = tile t+1's (per-wave FIFO);
//       trailing barrier makes all waves' DMA slices of buf b^1 visible.
//  Accumulation order kh0 then kh1 per acc element == rounds 0-4 -> bit-identical.
#define RGN 16384

#define DSR(d, b, imm) \
  asm volatile("ds_read_b128 %0, %1 offset:%c2" : "=&v"(d) : "v"(b), "i"(imm))

__global__ __launch_bounds__(512, 2) void gemm256(
    const unsigned short* __restrict__ act,  // M x K
    const unsigned short* __restrict__ Wlo,  // rows [0, Nsplit)
    const unsigned short* __restrict__ Whi,  // rows [Nsplit, N)
    const float* __restrict__ bias0, const float* __restrict__ bias1,
    int Nsplit, float* __restrict__ out, int Ndim, int K) {
  __shared__ unsigned char smA[65536];
  __shared__ unsigned char smB[65536];
  const int tid  = threadIdx.x;
  const int lane = tid & 63;
  const int w    = tid >> 6;           // 0..7
  const int waveM = w >> 2;            // 0..1  (128 rows each)
  const int waveN = w & 3;             // 0..3  (64 cols each)
  const int bm = blockIdx.x, bn = blockIdx.y;

  const unsigned short* Wp; int nbase;
  if (bn * 256 < Nsplit) { Wp = Wlo; nbase = bn * 256; }
  else                   { Wp = Whi; nbase = bn * 256 - Nsplit; }

  // per-lane ds_read byte offsets within a 16KB (buf,kh) region
  // logical slot = lane>>4; row-within-16 = lane&15; phys = logical ^ ((row>>1)&3)
  const int swz  = (((lane >> 4) ^ ((lane >> 1) & 3)) << 4);
  const int aoff = (waveM * 128 + (lane & 15)) * 64 + swz;
  const int boff = (waveN * 64  + (lane & 15)) * 64 + swz;

  const u32 baseA = (u32)(size_t)(void*)&smA[0] + (u32)aoff;
  const u32 baseB = (u32)(size_t)(void*)&smB[0] + (u32)boff;

  // staging: thread -> phys (row = half*128 + (tid>>2), slot = tid&3); fetch the
  // logical slot that belongs at that phys position: log = phys ^ ((row>>1)&3)
  const int srow = tid >> 2;
  const int slog = (tid & 3) ^ ((srow >> 1) & 3);
  const unsigned short* aS0 = act + (size_t)(bm * 256 + srow) * K + slog * 8;
  const unsigned short* aS1 = aS0 + (size_t)128 * K;
  const unsigned short* bS0 = Wp  + (size_t)(nbase + srow) * K + slog * 8;
  const unsigned short* bS1 = bS0 + (size_t)128 * K;
  const int wB = w * 1024;             // wave-uniform LDS byte base within an 8KB round

  f32x4 acc[8][4];
#pragma unroll
  for (int m = 0; m < 8; ++m)
#pragma unroll
    for (int n = 0; n < 4; ++n) acc[m][n] = (f32x4)0.0f;

  bf16x8 aA[4], aB[4], b0[4], b1[4];

#define STG(sm, g0, g1, t, kh, buf) do { \
    gload_lds16((g0) + (t) * 64 + (kh) * 32, (sm) + ((buf) * 2 + (kh)) * RGN + wB); \
    gload_lds16((g1) + (t) * 64 + (kh) * 32, (sm) + ((buf) * 2 + (kh)) * RGN + 8192 + wB); \
  } while (0)

#define STG4(t, buf) do { \
    STG(smA, aS0, aS1, t, 0, buf); \
    STG(smA, aS0, aS1, t, 1, buf); \
    STG(smB, bS0, bS1, t, 0, buf); \
    STG(smB, bS0, bS1, t, 1, buf); \
  } while (0)

#define VMW(n) do { \
    asm volatile("s_waitcnt vmcnt(" #n ")"); \
    __builtin_amdgcn_sched_barrier(0); \
  } while (0)

#define LGKM(n) do { \
    asm volatile("s_waitcnt lgkmcnt(" #n ")"); \
    __builtin_amdgcn_sched_barrier(0); \
  } while (0)

#define DSR4(ARR, base, off) do { \
    DSR(ARR[0], base, (off)); \
    DSR(ARR[1], base, (off) + 1024); \
    DSR(ARR[2], base, (off) + 2048); \
    DSR(ARR[3], base, (off) + 3072); \
  } while (0)

#define CL(ARR, BARR, MB) do { \
    __builtin_amdgcn_s_setprio(1); \
    _Pragma("unroll") \
    for (int _m = 0; _m < 4; ++_m) { \
      _Pragma("unroll") \
      for (int _n = 0; _n < 4; ++_n) \
        acc[(MB) + _m][_n] = __builtin_amdgcn_mfma_f32_16x16x32_bf16( \
            ARR[_m], BARR[_n], acc[(MB) + _m][_n], 0, 0, 0); \
    } \
    __builtin_amdgcn_s_setprio(0); \
  } while (0)

// compute body for the K-tile in buf (reads retired at LGKM(0))
#define BODY(buf) do { \
    DSR4(aA, baseA, ((buf) * 2 + 0) * RGN); \
    DSR4(b0, baseB, ((buf) * 2 + 0) * RGN); \
    DSR4(aB, baseA, ((buf) * 2 + 0) * RGN + 4096); \
    LGKM(4); \
    CL(aA, b0, 0); \
    DSR4(b1, baseB, ((buf) * 2 + 1) * RGN); \
    LGKM(4); \
    CL(aB, b0, 4); \
    DSR4(aA, baseA, ((buf) * 2 + 1) * RGN); \
    LGKM(4); \
    DSR4(aB, baseA, ((buf) * 2 + 1) * RGN + 4096); \
    LGKM(4); \
    CL(aA, b1, 0); \
    LGKM(0); \
    CL(aB, b1, 4); \
  } while (0)

// steady-state tile: compute buf, then stage t2 into the SAME buf, counted wait
#define TILEC(buf, t2) do { \
    BODY(buf); \
    __builtin_amdgcn_s_barrier(); \
    STG4(t2, buf); \
    VMW(8); \
    __builtin_amdgcn_s_barrier(); \
  } while (0)

  const int nkt   = K >> 6;   // K-tiles (even; >=16 for all shapes used here)
  const int niter = nkt >> 1;

  // prologue: tiles 0 and 1 staged; wait only tile 0 (tile 1 stays in flight)
  STG4(0, 0);
  STG4(1, 1);
  VMW(8);
  __builtin_amdgcn_s_barrier();

  for (int j = 0; j < niter - 1; ++j) {
    TILEC(0, 2 * j + 2);
    TILEC(1, 2 * j + 3);
  }
  // tile nkt-2: compute buf0; wait tile nkt-1's loads (only outstanding -> VMW(0))
  BODY(0);
  VMW(0);
  __builtin_amdgcn_s_barrier();
  // tile nkt-1: compute buf1, no further sync
  BODY(1);

#undef TILEC
#undef BODY
#undef CL
#undef DSR4
#undef LGKM
#undef VMW
#undef STG4
#undef STG

  const int colBase = bn * 256 + waveN * 64;
  const int rowBase = bm * 256 + waveM * 128;
#pragma unroll
  for (int m = 0; m < 8; ++m) {
#pragma unroll
    for (int n = 0; n < 4; ++n) {
      int col = colBase + n * 16 + (lane & 15);
      float bv = (col < Nsplit) ? bias0[col] : bias1[col - Nsplit];
#pragma unroll
      for (int r = 0; r < 4; ++r) {
        int row = rowBase + m * 16 + (lane >> 4) * 4 + r;
        out[(size_t)row * Ndim + col] = acc[m][n][r] + bv;
      }
    }
  }
}

// ---------------- pointwise helpers ----------------
__device__ __forceinline__ void gate_ab(float zp, float hp, float& a, float& bv) {
  float z  = 1.0f / (1.0f + __expf(-zp));
  float e  = __expf(-2.0f * fabsf(hp));
  float th = (1.0f - e) / (1.0f + e);
  th = (hp >= 0.0f) ? th : -th;
  a  = fminf(fmaxf(1.0f - z, 1e-8f), 1.0f - 1e-8f);
  bv = z * th;
}

// ---------------- scan pass 1: per-chunk composition ----------------
__global__ __launch_bounds__(256) void scan_p1(const float* __restrict__ pre,
                                               float* __restrict__ Ac, float* __restrict__ Bc,
                                               int dir) {
  int tid = threadIdx.x;
  int bid = blockIdx.x;
  int ht = bid & 3;
  int c  = (bid >> 2) & (NCH - 1);
  int b  = bid >> 8;
  int h  = ht * 256 + tid;
  float Aa = 1.0f, Bb = 0.0f;
  for (int j = 0; j < CHUNK; ++j) {
    int t = c * CHUNK + j;
    int s = dir ? (Sn - 1 - t) : t;
    const float* p = pre + (size_t)(b * Sn + s) * 2048;
    float a, bv;
    gate_ab(p[h], p[1024 + h], a, bv);
    Aa = a * Aa;
    Bb = a * Bb + bv;
  }
  Ac[(size_t)(b * NCH + c) * Hn + h] = Aa;
  Bc[(size_t)(b * NCH + c) * Hn + h] = Bb;
}

// ---------------- scan mid: prefix across chunks ----------------
__global__ __launch_bounds__(256) void scan_mid(const float* __restrict__ Ac,
                                                const float* __restrict__ Bc,
                                                float* __restrict__ pref) {
  int tid = blockIdx.x * 256 + threadIdx.x;
  int b = tid >> 10;
  int h = tid & 1023;
  float run = 0.0f;
  for (int c = 0; c < NCH; ++c) {
    size_t idx = (size_t)(b * NCH + c) * Hn + h;
    pref[idx] = run;
    run = Ac[idx] * run + Bc[idx];
  }
}

// ---------------- scan pass 3 FUSED with LayerNorm(+residual) ----------------
// ROUND-5: eliminates the hs round-trip (64 MB/layer-dir) and the separate ln
// dispatch. One block per (b, chunk): 1024 threads (one per h), 32 sequential
// timesteps; per-step block-wide LN reduction via wave shuffle + 16 LDS partials
// (double-buffered -> single barrier/step). h-recurrence and gate math identical
// to the old scan_p3; LN sum order differs at ulp level only. resid/out_f32 may
// alias (in-place row update: read-before-write within each thread, same as the
// old ln_kernel).
__global__ __launch_bounds__(1024) void scan_p3_ln(
    const float* __restrict__ pre, const float* __restrict__ pref,
    const float* __restrict__ resid,
    const float* __restrict__ gamma, const float* __restrict__ beta,
    float* __restrict__ out_f32, unsigned short* __restrict__ out_bf,
    int bf_stride, int bf_off, int dir) {
  __shared__ float2 part[2][16];
  const int h   = threadIdx.x;
  const int c   = blockIdx.x & (NCH - 1);
  const int b   = blockIdx.x >> 6;       // NCH = 64
  const int lane = h & 63, wid = h >> 6;
  const float g  = gamma[h];
  const float be = beta[h];
  float hprev = pref[(size_t)(b * NCH + c) * Hn + h];

  // 1-step-ahead prefetch of the independent loads (pre pair + resid)
  int t0 = c * CHUNK;
  int s0 = dir ? (Sn - 1 - t0) : t0;
  const float* p0 = pre + (size_t)(b * Sn + s0) * 2048;
  float zp = p0[h], hp = p0[1024 + h];
  float rv = resid ? resid[(size_t)(b * Sn + s0) * Hn + h] : 0.0f;

  for (int j = 0; j < CHUNK; ++j) {
    int t = c * CHUNK + j;
    int s = dir ? (Sn - 1 - t) : t;
    float zc = zp, hc = hp, rc = rv;
    if (j + 1 < CHUNK) {
      int t1 = t + 1;
      int s1 = dir ? (Sn - 1 - t1) : t1;
      const float* p1 = pre + (size_t)(b * Sn + s1) * 2048;
      zp = p1[h]; hp = p1[1024 + h];
      rv = resid ? resid[(size_t)(b * Sn + s1) * Hn + h] : 0.0f;
    }
    float a, bv;
    gate_ab(zc, hc, a, bv);
    hprev = a * hprev + bv;
    float v = hprev + rc;
    // block-wide sum of v and v^2
    float r1 = v, r2 = v * v;
#pragma unroll
    for (int off = 1; off < 64; off <<= 1) {
      r1 += __shfl_xor(r1, off);
      r2 += __shfl_xor(r2, off);
    }
    if (lane == 0) part[j & 1][wid] = make_float2(r1, r2);
    __syncthreads();
    float s1v = 0.0f, s2v = 0.0f;
#pragma unroll
    for (int q = 0; q < 16; ++q) {
      float2 pq = part[j & 1][q];
      s1v += pq.x; s2v += pq.y;
    }
    float mu  = s1v * (1.0f / Hn);
    float var = s2v * (1.0f / Hn) - mu * mu;
    float rs  = rsqrtf(var + 1e-5f);
    float o = (v - mu) * rs * g + be;
    size_t row = (size_t)(b * Sn + s);
    if (out_f32) out_f32[row * Hn + h] = o;
    out_bf[row * bf_stride + bf_off + h] = f2bf(o);
  }
}

// ---------------- launcher ----------------
extern "C" void kernel_launch(void* const* d_in, const int* in_sizes, int n_in,
                              void* d_out, int out_size, void* d_ws, size_t ws_size,
                              hipStream_t stream) {
  const float* x        = (const float*)d_in[0];
  const float* fwd_Wz   = (const float*)d_in[1];
  const float* fwd_bz   = (const float*)d_in[2];
  const float* fwd_Wh   = (const float*)d_in[3];
  const float* fwd_bh   = (const float*)d_in[4];
  const float* bwd_Wz   = (const float*)d_in[5];
  const float* bwd_bz   = (const float*)d_in[6];
  const float* bwd_Wh   = (const float*)d_in[7];
  const float* bwd_bh   = (const float*)d_in[8];
  const float* fusion_W = (const float*)d_in[9];
  const float* fusion_b = (const float*)d_in[10];
  const float* gamma    = (const float*)d_in[11];
  const float* beta     = (const float*)d_in[12];
  float* out = (float*)d_out;

  // workspace layout (hs slot retained but unused after the p3+LN fusion)
  unsigned short* WzA    = (unsigned short*)d_ws;              // 2*4*1024*1024
  unsigned short* WhA    = WzA + 8ULL * 1024 * 1024;           // 2*4*1024*1024
  unsigned short* fusWbf = WhA + 8ULL * 1024 * 1024;           // 1024*2048
  unsigned short* xbf    = fusWbf + 2ULL * 1024 * 1024;        // 8192*1024
  unsigned short* actbf  = xbf + 8ULL * 1024 * 1024;           // 8192*1024
  unsigned short* combbf = actbf + 8ULL * 1024 * 1024;         // 8192*2048
  float* actf = (float*)(combbf + 16ULL * 1024 * 1024);        // 8192*1024
  float* pre  = actf + 8ULL * 1024 * 1024;                     // 8192*2048
  float* hs   = pre + 16ULL * 1024 * 1024;                     // 8192*1024 (unused)
  float* Ac   = hs + 8ULL * 1024 * 1024;                       // 4*NCH*1024
  float* Bc   = Ac + (size_t)Bn * NCH * Hn;
  float* pref = Bc + (size_t)Bn * NCH * Hn;
  size_t need = (size_t)((char*)(pref + (size_t)Bn * NCH * Hn) - (char*)d_ws);
  if (ws_size < need) return;

  auto cast = [&](const float* src, unsigned short* dst, size_t n) {
    int n4 = (int)(n / 4);
    cast_f32_bf16<<<(n4 + 255) / 256, 256, 0, stream>>>(src, dst, n4);
  };
  cast(fwd_Wz, WzA,                     4ULL * 1024 * 1024);
  cast(bwd_Wz, WzA + 4ULL * 1024 * 1024, 4ULL * 1024 * 1024);
  cast(fwd_Wh, WhA,                     4ULL * 1024 * 1024);
  cast(bwd_Wh, WhA + 4ULL * 1024 * 1024, 4ULL * 1024 * 1024);
  cast(fusion_W, fusWbf, 2ULL * 1024 * 1024);
  cast(x, xbf, 8ULL * 1024 * 1024);

  for (int d = 0; d < 2; ++d) {
    const float* bz = d ? bwd_bz : fwd_bz;
    const float* bh = d ? bwd_bh : fwd_bh;
    for (int l = 0; l < Ln; ++l) {
      const unsigned short* a_in = (l == 0) ? xbf : actbf;
      const unsigned short* Wlo = WzA + (size_t)(d * 4 + l) * 1024 * 1024;
      const unsigned short* Whi = WhA + (size_t)(d * 4 + l) * 1024 * 1024;
      gemm256<<<dim3(Mn / 256, 2048 / 256), 512, 0, stream>>>(
          a_in, Wlo, Whi, bz + l * 1024, bh + l * 1024, 1024, pre, 2048, 1024);
      scan_p1<<<Bn * NCH * 4, 256, 0, stream>>>(pre, Ac, Bc, d);
      scan_mid<<<16, 256, 0, stream>>>(Ac, Bc, pref);
      if (l < Ln - 1)
        scan_p3_ln<<<Bn * NCH, 1024, 0, stream>>>(
            pre, pref, (l == 0) ? nullptr : actf, gamma, beta,
            actf, actbf, 1024, 0, d);
      else
        scan_p3_ln<<<Bn * NCH, 1024, 0, stream>>>(
            pre, pref, actf, gamma, beta,
            nullptr, combbf, 2048, d * 1024, d);
    }
  }
  // fusion: out = comb(bf16) @ fusion_W^T + fusion_b
  gemm256<<<dim3(Mn / 256, 1024 / 256), 512, 0, stream>>>(
      combbf, fusWbf, fusWbf, fusion_b, fusion_b, 1 << 30, out, 1024, 2048);
}

// Round 6
// 809.735 us; speedup vs baseline: 1.1551x; 1.1551x over previous
//
#include <hip/hip_runtime.h>
#include <stdint.h>

#define Bn 4
#define Sn 2048
#define Hn 1024
#define Ln 4
#define Mn (Bn*Sn)          // 8192 rows
#define CHUNK 32
#define NCH (Sn/CHUNK)      // 64

typedef __bf16 bf16x8 __attribute__((ext_vector_type(8)));
typedef float  f32x4  __attribute__((ext_vector_type(4)));
typedef uint32_t u32;

__device__ __forceinline__ unsigned short f2bf(float f) {
  uint32_t u = __float_as_uint(f);
  uint32_t r = (u + 0x7FFFu + ((u >> 16) & 1u)) >> 16;
  return (unsigned short)r;
}
__device__ __forceinline__ float bf2f(unsigned short u) {
  return __uint_as_float(((uint32_t)u) << 16);
}

__device__ __forceinline__ void gload_lds16(const void* g, void* l) {
  __builtin_amdgcn_global_load_lds((const __attribute__((address_space(1))) void*)g,
                                   (__attribute__((address_space(3))) void*)l, 16, 0, 0);
}

// ---------------- cast f32 -> bf16 (vectorized) ----------------
__global__ __launch_bounds__(256) void cast_f32_bf16(const float* __restrict__ src,
                                                     unsigned short* __restrict__ dst, int n4) {
  int i = blockIdx.x * 256 + threadIdx.x;
  if (i >= n4) return;
  float4 v = reinterpret_cast<const float4*>(src)[i];
  ushort4 o;
  o.x = f2bf(v.x); o.y = f2bf(v.y); o.z = f2bf(v.z); o.w = f2bf(v.w);
  reinterpret_cast<ushort4*>(dst)[i] = o;
}

// ---------------- GEMM: out[M,N] = act[M,K](bf16) @ W[N,K]^T (bf16) + bias ----------------
// ROUND-6: exact round-4 structure (best measured: 57 us/dispatch) — one barrier +
// one vmcnt per K-tile, counted lgkm gates intra-tile, asm ds_read_b128, 2-way
// slot-XOR swizzle (0 bank conflicts), setprio on MFMA clusters. Round-5's depth-2
// prefetch REGRESSED (57->64: extra barrier+VMW(8) cost more than the drain it
// removed) and is reverted. New: optional bf16 epilogue (outbf != nullptr) halves
// the pre-activation write traffic; fusion GEMM still writes f32.
#define RGN 16384

#define DSR(d, b, imm) \
  asm volatile("ds_read_b128 %0, %1 offset:%c2" : "=&v"(d) : "v"(b), "i"(imm))

__global__ __launch_bounds__(512, 2) void gemm256(
    const unsigned short* __restrict__ act,  // M x K
    const unsigned short* __restrict__ Wlo,  // rows [0, Nsplit)
    const unsigned short* __restrict__ Whi,  // rows [Nsplit, N)
    const float* __restrict__ bias0, const float* __restrict__ bias1,
    int Nsplit, float* __restrict__ out, unsigned short* __restrict__ outbf,
    int Ndim, int K) {
  __shared__ unsigned char smA[65536];
  __shared__ unsigned char smB[65536];
  const int tid  = threadIdx.x;
  const int lane = tid & 63;
  const int w    = tid >> 6;           // 0..7
  const int waveM = w >> 2;            // 0..1  (128 rows each)
  const int waveN = w & 3;             // 0..3  (64 cols each)
  const int bm = blockIdx.x, bn = blockIdx.y;

  const unsigned short* Wp; int nbase;
  if (bn * 256 < Nsplit) { Wp = Wlo; nbase = bn * 256; }
  else                   { Wp = Whi; nbase = bn * 256 - Nsplit; }

  // per-lane ds_read byte offsets within a 16KB (buf,kh) region
  // logical slot = lane>>4; row-within-16 = lane&15; phys = logical ^ ((row>>1)&3)
  const int swz  = (((lane >> 4) ^ ((lane >> 1) & 3)) << 4);
  const int aoff = (waveM * 128 + (lane & 15)) * 64 + swz;
  const int boff = (waveN * 64  + (lane & 15)) * 64 + swz;

  const u32 baseA = (u32)(size_t)(void*)&smA[0] + (u32)aoff;
  const u32 baseB = (u32)(size_t)(void*)&smB[0] + (u32)boff;

  // staging: thread -> phys (row = half*128 + (tid>>2), slot = tid&3); fetch the
  // logical slot that belongs at that phys position: log = phys ^ ((row>>1)&3)
  const int srow = tid >> 2;
  const int slog = (tid & 3) ^ ((srow >> 1) & 3);
  const unsigned short* aS0 = act + (size_t)(bm * 256 + srow) * K + slog * 8;
  const unsigned short* aS1 = aS0 + (size_t)128 * K;
  const unsigned short* bS0 = Wp  + (size_t)(nbase + srow) * K + slog * 8;
  const unsigned short* bS1 = bS0 + (size_t)128 * K;
  const int wB = w * 1024;             // wave-uniform LDS byte base within an 8KB round

  f32x4 acc[8][4];
#pragma unroll
  for (int m = 0; m < 8; ++m)
#pragma unroll
    for (int n = 0; n < 4; ++n) acc[m][n] = (f32x4)0.0f;

  bf16x8 aA[4], aB[4], b0[4], b1[4];

#define STG(sm, g0, g1, t, kh, buf) do { \
    gload_lds16((g0) + (t) * 64 + (kh) * 32, (sm) + ((buf) * 2 + (kh)) * RGN + wB); \
    gload_lds16((g1) + (t) * 64 + (kh) * 32, (sm) + ((buf) * 2 + (kh)) * RGN + 8192 + wB); \
  } while (0)

#define STG4(t, buf) do { \
    STG(smA, aS0, aS1, t, 0, buf); \
    STG(smA, aS0, aS1, t, 1, buf); \
    STG(smB, bS0, bS1, t, 0, buf); \
    STG(smB, bS0, bS1, t, 1, buf); \
  } while (0)

#define VMW(n) do { \
    asm volatile("s_waitcnt vmcnt(" #n ")"); \
    __builtin_amdgcn_sched_barrier(0); \
  } while (0)

#define LGKM(n) do { \
    asm volatile("s_waitcnt lgkmcnt(" #n ")"); \
    __builtin_amdgcn_sched_barrier(0); \
  } while (0)

#define DSR4(ARR, base, off) do { \
    DSR(ARR[0], base, (off)); \
    DSR(ARR[1], base, (off) + 1024); \
    DSR(ARR[2], base, (off) + 2048); \
    DSR(ARR[3], base, (off) + 3072); \
  } while (0)

#define CL(ARR, BARR, MB) do { \
    __builtin_amdgcn_s_setprio(1); \
    _Pragma("unroll") \
    for (int _m = 0; _m < 4; ++_m) { \
      _Pragma("unroll") \
      for (int _n = 0; _n < 4; ++_n) \
        acc[(MB) + _m][_n] = __builtin_amdgcn_mfma_f32_16x16x32_bf16( \
            ARR[_m], BARR[_n], acc[(MB) + _m][_n], 0, 0, 0); \
    } \
    __builtin_amdgcn_s_setprio(0); \
  } while (0)

#define TILE(buf, STAGE_STMT, END_STMT) do { \
    STAGE_STMT \
    DSR4(aA, baseA, ((buf) * 2 + 0) * RGN); \
    DSR4(b0, baseB, ((buf) * 2 + 0) * RGN); \
    DSR4(aB, baseA, ((buf) * 2 + 0) * RGN + 4096); \
    LGKM(4); \
    CL(aA, b0, 0); \
    DSR4(b1, baseB, ((buf) * 2 + 1) * RGN); \
    LGKM(4); \
    CL(aB, b0, 4); \
    DSR4(aA, baseA, ((buf) * 2 + 1) * RGN); \
    LGKM(4); \
    DSR4(aB, baseA, ((buf) * 2 + 1) * RGN + 4096); \
    LGKM(4); \
    CL(aA, b1, 0); \
    LGKM(0); \
    CL(aB, b1, 4); \
    END_STMT \
  } while (0)

  const int nkt   = K >> 6;   // K-tiles (even; >=16 for all shapes used here)
  const int niter = nkt >> 1;

  // prologue: stage tile 0 into buf0
  STG4(0, 0);
  VMW(0);
  __builtin_amdgcn_s_barrier();

  for (int j = 0; j < niter - 1; ++j) {
    TILE(0, STG4(2 * j + 1, 1);, VMW(0); __builtin_amdgcn_s_barrier(); );
    TILE(1, STG4(2 * j + 2, 0);, VMW(0); __builtin_amdgcn_s_barrier(); );
  }
  TILE(0, STG4(nkt - 1, 1);, VMW(0); __builtin_amdgcn_s_barrier(); );
  TILE(1, , );

#undef TILE
#undef CL
#undef DSR4
#undef LGKM
#undef VMW
#undef STG4
#undef STG

  const int colBase = bn * 256 + waveN * 64;
  const int rowBase = bm * 256 + waveM * 128;
#pragma unroll
  for (int m = 0; m < 8; ++m) {
#pragma unroll
    for (int n = 0; n < 4; ++n) {
      int col = colBase + n * 16 + (lane & 15);
      float bv = (col < Nsplit) ? bias0[col] : bias1[col - Nsplit];
      if (outbf) {
#pragma unroll
        for (int r = 0; r < 4; ++r) {
          int row = rowBase + m * 16 + (lane >> 4) * 4 + r;
          outbf[(size_t)row * Ndim + col] = f2bf(acc[m][n][r] + bv);
        }
      } else {
#pragma unroll
        for (int r = 0; r < 4; ++r) {
          int row = rowBase + m * 16 + (lane >> 4) * 4 + r;
          out[(size_t)row * Ndim + col] = acc[m][n][r] + bv;
        }
      }
    }
  }
}

// ---------------- pointwise helpers ----------------
__device__ __forceinline__ void gate_ab(float zp, float hp, float& a, float& bv) {
  float z  = 1.0f / (1.0f + __expf(-zp));
  float e  = __expf(-2.0f * fabsf(hp));
  float th = (1.0f - e) / (1.0f + e);
  th = (hp >= 0.0f) ? th : -th;
  a  = fminf(fmaxf(1.0f - z, 1e-8f), 1.0f - 1e-8f);
  bv = z * th;
}

// ---------------- scan pass 1: per-chunk composition (bf16 pre) ----------------
__global__ __launch_bounds__(256) void scan_p1(const unsigned short* __restrict__ pre,
                                               float* __restrict__ Ac, float* __restrict__ Bc,
                                               int dir) {
  int tid = threadIdx.x;
  int bid = blockIdx.x;
  int ht = bid & 3;
  int c  = (bid >> 2) & (NCH - 1);
  int b  = bid >> 8;
  int h  = ht * 256 + tid;
  float Aa = 1.0f, Bb = 0.0f;
  for (int j = 0; j < CHUNK; ++j) {
    int t = c * CHUNK + j;
    int s = dir ? (Sn - 1 - t) : t;
    const unsigned short* p = pre + (size_t)(b * Sn + s) * 2048;
    float a, bv;
    gate_ab(bf2f(p[h]), bf2f(p[1024 + h]), a, bv);
    Aa = a * Aa;
    Bb = a * Bb + bv;
  }
  Ac[(size_t)(b * NCH + c) * Hn + h] = Aa;
  Bc[(size_t)(b * NCH + c) * Hn + h] = Bb;
}

// ---------------- scan mid: prefix across chunks ----------------
__global__ __launch_bounds__(256) void scan_mid(const float* __restrict__ Ac,
                                                const float* __restrict__ Bc,
                                                float* __restrict__ pref) {
  int tid = blockIdx.x * 256 + threadIdx.x;
  int b = tid >> 10;
  int h = tid & 1023;
  float run = 0.0f;
  for (int c = 0; c < NCH; ++c) {
    size_t idx = (size_t)(b * NCH + c) * Hn + h;
    pref[idx] = run;
    run = Ac[idx] * run + Bc[idx];
  }
}

// ---------------- scan pass 3: apply (bf16 pre) ----------------
__global__ __launch_bounds__(256) void scan_p3(const unsigned short* __restrict__ pre,
                                               const float* __restrict__ pref,
                                               float* __restrict__ hs, int dir) {
  int tid = threadIdx.x;
  int bid = blockIdx.x;
  int ht = bid & 3;
  int c  = (bid >> 2) & (NCH - 1);
  int b  = bid >> 8;
  int h  = ht * 256 + tid;
  float hprev = pref[(size_t)(b * NCH + c) * Hn + h];
  for (int j = 0; j < CHUNK; ++j) {
    int t = c * CHUNK + j;
    int s = dir ? (Sn - 1 - t) : t;
    const unsigned short* p = pre + (size_t)(b * Sn + s) * 2048;
    float a, bv;
    gate_ab(bf2f(p[h]), bf2f(p[1024 + h]), a, bv);
    hprev = a * hprev + bv;
    hs[(size_t)(b * Sn + s) * Hn + h] = hprev;
  }
}

// ---------------- LayerNorm (+residual), writes f32 + bf16 ----------------
__global__ __launch_bounds__(256) void ln_kernel(const float* __restrict__ hs,
                                                 const float* __restrict__ resid,
                                                 const float* __restrict__ gamma,
                                                 const float* __restrict__ beta,
                                                 float* __restrict__ out_f32,
                                                 unsigned short* __restrict__ out_bf,
                                                 int bf_stride, int bf_off) {
  int row  = blockIdx.x * 4 + (threadIdx.x >> 6);
  int lane = threadIdx.x & 63;
  const float4* hr = reinterpret_cast<const float4*>(hs + (size_t)row * Hn);
  const float4* rr = resid ? reinterpret_cast<const float4*>(resid + (size_t)row * Hn) : nullptr;
  float v[16];
  float s1 = 0.0f, s2 = 0.0f;
#pragma unroll
  for (int j = 0; j < 4; ++j) {
    float4 t = hr[j * 64 + lane];
    if (rr) {
      float4 q = rr[j * 64 + lane];
      t.x += q.x; t.y += q.y; t.z += q.z; t.w += q.w;
    }
    v[j*4+0] = t.x; v[j*4+1] = t.y; v[j*4+2] = t.z; v[j*4+3] = t.w;
    s1 += t.x + t.y + t.z + t.w;
    s2 += t.x*t.x + t.y*t.y + t.z*t.z + t.w*t.w;
  }
#pragma unroll
  for (int off = 1; off < 64; off <<= 1) {
    s1 += __shfl_xor(s1, off);
    s2 += __shfl_xor(s2, off);
  }
  float mu  = s1 * (1.0f / Hn);
  float var = s2 * (1.0f / Hn) - mu * mu;
  float rs  = rsqrtf(var + 1e-5f);
#pragma unroll
  for (int j = 0; j < 4; ++j) {
    float4 g  = reinterpret_cast<const float4*>(gamma)[j * 64 + lane];
    float4 be = reinterpret_cast<const float4*>(beta)[j * 64 + lane];
    float4 o;
    o.x = (v[j*4+0] - mu) * rs * g.x + be.x;
    o.y = (v[j*4+1] - mu) * rs * g.y + be.y;
    o.z = (v[j*4+2] - mu) * rs * g.z + be.z;
    o.w = (v[j*4+3] - mu) * rs * g.w + be.w;
    if (out_f32)
      reinterpret_cast<float4*>(out_f32 + (size_t)row * Hn)[j * 64 + lane] = o;
    ushort4 ob;
    ob.x = f2bf(o.x); ob.y = f2bf(o.y); ob.z = f2bf(o.z); ob.w = f2bf(o.w);
    reinterpret_cast<ushort4*>(out_bf + (size_t)row * bf_stride + bf_off)[j * 64 + lane] = ob;
  }
}

// ---------------- launcher ----------------
extern "C" void kernel_launch(void* const* d_in, const int* in_sizes, int n_in,
                              void* d_out, int out_size, void* d_ws, size_t ws_size,
                              hipStream_t stream) {
  const float* x        = (const float*)d_in[0];
  const float* fwd_Wz   = (const float*)d_in[1];
  const float* fwd_bz   = (const float*)d_in[2];
  const float* fwd_Wh   = (const float*)d_in[3];
  const float* fwd_bh   = (const float*)d_in[4];
  const float* bwd_Wz   = (const float*)d_in[5];
  const float* bwd_bz   = (const float*)d_in[6];
  const float* bwd_Wh   = (const float*)d_in[7];
  const float* bwd_bh   = (const float*)d_in[8];
  const float* fusion_W = (const float*)d_in[9];
  const float* fusion_b = (const float*)d_in[10];
  const float* gamma    = (const float*)d_in[11];
  const float* beta     = (const float*)d_in[12];
  float* out = (float*)d_out;

  // workspace layout (pre slot now holds bf16 pre-activations, 33.5 MB of its 67 MB)
  unsigned short* WzA    = (unsigned short*)d_ws;              // 2*4*1024*1024
  unsigned short* WhA    = WzA + 8ULL * 1024 * 1024;           // 2*4*1024*1024
  unsigned short* fusWbf = WhA + 8ULL * 1024 * 1024;           // 1024*2048
  unsigned short* xbf    = fusWbf + 2ULL * 1024 * 1024;        // 8192*1024
  unsigned short* actbf  = xbf + 8ULL * 1024 * 1024;           // 8192*1024
  unsigned short* combbf = actbf + 8ULL * 1024 * 1024;         // 8192*2048
  float* actf = (float*)(combbf + 16ULL * 1024 * 1024);        // 8192*1024
  float* pre  = actf + 8ULL * 1024 * 1024;                     // 8192*2048 (bf16 uses half)
  float* hs   = pre + 16ULL * 1024 * 1024;                     // 8192*1024
  float* Ac   = hs + 8ULL * 1024 * 1024;                       // 4*NCH*1024
  float* Bc   = Ac + (size_t)Bn * NCH * Hn;
  float* pref = Bc + (size_t)Bn * NCH * Hn;
  size_t need = (size_t)((char*)(pref + (size_t)Bn * NCH * Hn) - (char*)d_ws);
  if (ws_size < need) return;
  unsigned short* prebf = (unsigned short*)pre;

  auto cast = [&](const float* src, unsigned short* dst, size_t n) {
    int n4 = (int)(n / 4);
    cast_f32_bf16<<<(n4 + 255) / 256, 256, 0, stream>>>(src, dst, n4);
  };
  cast(fwd_Wz, WzA,                     4ULL * 1024 * 1024);
  cast(bwd_Wz, WzA + 4ULL * 1024 * 1024, 4ULL * 1024 * 1024);
  cast(fwd_Wh, WhA,                     4ULL * 1024 * 1024);
  cast(bwd_Wh, WhA + 4ULL * 1024 * 1024, 4ULL * 1024 * 1024);
  cast(fusion_W, fusWbf, 2ULL * 1024 * 1024);
  cast(x, xbf, 8ULL * 1024 * 1024);

  for (int d = 0; d < 2; ++d) {
    const float* bz = d ? bwd_bz : fwd_bz;
    const float* bh = d ? bwd_bh : fwd_bh;
    for (int l = 0; l < Ln; ++l) {
      const unsigned short* a_in = (l == 0) ? xbf : actbf;
      const unsigned short* Wlo = WzA + (size_t)(d * 4 + l) * 1024 * 1024;
      const unsigned short* Whi = WhA + (size_t)(d * 4 + l) * 1024 * 1024;
      gemm256<<<dim3(Mn / 256, 2048 / 256), 512, 0, stream>>>(
          a_in, Wlo, Whi, bz + l * 1024, bh + l * 1024, 1024,
          nullptr, prebf, 2048, 1024);
      scan_p1<<<Bn * NCH * 4, 256, 0, stream>>>(prebf, Ac, Bc, d);
      scan_mid<<<16, 256, 0, stream>>>(Ac, Bc, pref);
      scan_p3<<<Bn * NCH * 4, 256, 0, stream>>>(prebf, pref, hs, d);
      if (l < Ln - 1)
        ln_kernel<<<Mn / 4, 256, 0, stream>>>(hs, (l == 0) ? nullptr : actf,
                                              gamma, beta, actf, actbf, 1024, 0);
      else
        ln_kernel<<<Mn / 4, 256, 0, stream>>>(hs, actf, gamma, beta,
                                              nullptr, combbf, 2048, d * 1024);
    }
  }
  // fusion: out = comb(bf16) @ fusion_W^T + fusion_b (f32 output)
  gemm256<<<dim3(Mn / 256, 1024 / 256), 512, 0, stream>>>(
      combbf, fusWbf, fusWbf, fusion_b, fusion_b, 1 << 30, out, nullptr, 1024, 2048);
}